// Round 6
// baseline (241.519 us; speedup 1.0000x reference)
//
#include <hip/hip_runtime.h>
#include <hip/hip_bf16.h>
#include <math.h>
#include <stdint.h>

// Problem constants (fixed by the reference)
#define S_LEN  8192
#define DMODEL 512
#define NBATCH 4

// gemm_m tiling: R0-proven 256x256 tile, 512 threads, two-__syncthreads loop
// (best measured: 63 us). R6 adds ONLY the R1-proven XCD swizzle (FETCH
// 131->71 MB in R1; R1's dur regression is attributed to its barrier
// restructure, which is reverted here) and a kt-contiguous partial layout.
constexpr int TM = 256, TN = 256, BK = 32;
constexpr int PK = 40;                    // padded LDS row stride (shorts)

// gemm_cr tiling
constexpr int PKC = 40;

// Workspace: Mpart @ 0 (NBATCH*NS*4 tiles x 256 KB; NS=16 -> 64 MB),
//            vpart after (NS*NBATCH*4 rows x 2 KB).
// No Mred / vws: the reduce kernel is fused into gemm_cr.
__host__ __device__ constexpr size_t mpart_elems(int ns) {
  return (size_t)NBATCH * ns * 4 * (TM * TN);
}
__host__ __device__ constexpr size_t vpart_elems(int ns) {
  return (size_t)ns * NBATCH * 4 * DMODEL;
}
__host__ __device__ constexpr size_t ws_need(int ns) {
  return (mpart_elems(ns) + vpart_elems(ns)) * 4;   // 67.6 MB @ NS=16
}

typedef short bfrag  __attribute__((ext_vector_type(8)));   // 8 bf16 (4 VGPRs)
typedef float facc   __attribute__((ext_vector_type(4)));   // 4 fp32 acc

__device__ __forceinline__ unsigned pk2(float a, float b) {
  __hip_bfloat162 t = __float22bfloat162_rn(make_float2(a, b));  // v_cvt_pk_bf16_f32
  union { __hip_bfloat162 h; unsigned u; } cc; cc.h = t; return cc.u;
}

__device__ __forceinline__ float selc(const float4& v, int c) {
  return c == 0 ? v.x : c == 1 ? v.y : c == 2 ? v.z : v.w;
}

// ---------------------------------------------------------------------------
// Kernel 1: partial M[b][d'][d] = sum_{t in chunk} w_t h[b][t][d'] e[b][t][d]
// R0 body verbatim (63 us best-measured): 256x256 tile, waves 0-3 stage A(h),
// waves 4-7 stage B(e), register-prefetch, packed bf16 convert, two barriers.
// Swizzle: XCD x = sidx&7 gets logical blocks [x*32, x*32+32) = one bb, a
// contiguous kt-range, all 4 (mt,nt) -> h/e panel reuse stays in-XCD (R1:
// FETCH 131->71 MB). Partial tiles stored kt-contiguous per position g so
// gemm_cr's kt-sum streams 256KB-strided tiles.
// ---------------------------------------------------------------------------
template <int NS>
__global__ __launch_bounds__(512, 2) void gemm_m_kernel(
    const float* __restrict__ h, const float* __restrict__ e,
    float* __restrict__ Mout, float* __restrict__ vout)
{
  __shared__ short Al[TM * PK];   // 20 KB
  __shared__ short Bl[TN * PK];   // 20 KB

  constexpr int KCH = S_LEN / NS;

  // bijective XCD swizzle (grid % 8 == 0)
  const int sidx = blockIdx.x;
  const int blk  = (sidx & 7) * (int)(gridDim.x >> 3) + (sidx >> 3);

  const int nt  = blk & 1;
  const int mt  = (blk >> 1) & 1;
  const int kt  = (blk >> 2) % NS;
  const int bb  = blk / (4 * NS);

  const int tid   = threadIdx.x;
  const bool isB  = (tid >= 256);      // wave-uniform (waves 4..7)
  const int hid   = tid & 255;
  const int col4  = (hid >> 2) * 4;    // 0..252 within the 256-wide tile
  const int trow  = hid & 3;           // t-rows trow*8 .. trow*8+7

  const int wv   = tid >> 6;           // 8 waves -> 2x4 of 128x64 subtiles
  const int wm   = wv >> 2;            // 0..1 (row half)
  const int wn   = wv & 3;             // 0..3 (col quarter)
  const int lane = tid & 63;
  const int lm   = lane & 15, q = lane >> 4;

  const float* src = (isB ? e : h) + (size_t)bb * S_LEN * DMODEL
                   + (isB ? nt * TN : mt * TM) + col4;
  short* ldst = (isB ? Bl : Al) + col4 * PK + trow * 8;

  facc acc[8][4];
#pragma unroll
  for (int i = 0; i < 8; ++i)
#pragma unroll
    for (int j = 0; j < 4; ++j) acc[i][j] = (facc){0.f, 0.f, 0.f, 0.f};

  const float lnA = -(float)M_PI / (float)S_LEN;   // log(alpha), negative
  const int tstart = kt * KCH, tend = tstart + KCH;

  float wbase = __expf(lnA * (float)(S_LEN - 1 - tstart - trow * 8));
  const float stepw = __expf(-lnA * (float)BK);    // alpha^(-32)
  float cr[8];
#pragma unroll
  for (int r = 0; r < 8; ++r)
    cr[r] = __expf(-lnA * (float)r);               // alpha^(-r)

  float4 vacc4 = {0.f, 0.f, 0.f, 0.f};

  // ---- preload iter 0 ----
  float4 cur[8];
  {
    const float* p = src + (size_t)(tstart + trow * 8) * DMODEL;
#pragma unroll
    for (int r = 0; r < 8; ++r) cur[r] = *(const float4*)(p + (size_t)r * DMODEL);
  }

  for (int t0 = tstart; t0 < tend; t0 += BK) {
    // ---- scale (B only) + v accumulate ----
    if (isB) {
#pragma unroll
      for (int r = 0; r < 8; ++r) {
        const float w = wbase * cr[r];
        cur[r].x *= w; cur[r].y *= w; cur[r].z *= w; cur[r].w *= w;
      }
      if (mt == 0) {
#pragma unroll
        for (int r = 0; r < 8; ++r) {
          vacc4.x += cur[r].x; vacc4.y += cur[r].y;
          vacc4.z += cur[r].z; vacc4.w += cur[r].w;
        }
      }
    }
    wbase *= stepw;

    // ---- packed bf16 convert + register transpose (frees cur) ----
    uint4 pk[4];
#pragma unroll
    for (int c = 0; c < 4; ++c) {
      pk[c].x = pk2(selc(cur[0], c), selc(cur[1], c));
      pk[c].y = pk2(selc(cur[2], c), selc(cur[3], c));
      pk[c].z = pk2(selc(cur[4], c), selc(cur[5], c));
      pk[c].w = pk2(selc(cur[6], c), selc(cur[7], c));
    }

    // ---- issue next tile's loads (prefetch distance ~= one iteration) ----
    if (t0 + BK < tend) {
      const float* p = src + (size_t)(t0 + BK + trow * 8) * DMODEL;
#pragma unroll
      for (int r = 0; r < 8; ++r) cur[r] = *(const float4*)(p + (size_t)r * DMODEL);
    }

    __syncthreads();   // previous iteration's frag reads done
#pragma unroll
    for (int c = 0; c < 4; ++c)
      *(uint4*)(ldst + c * PK) = pk[c];
    __syncthreads();

    bfrag af[8], bf[4];
#pragma unroll
    for (int i = 0; i < 8; ++i)
      af[i] = *(const bfrag*)&Al[(wm * 128 + i * 16 + lm) * PK + q * 8];
#pragma unroll
    for (int j = 0; j < 4; ++j)
      bf[j] = *(const bfrag*)&Bl[(wn * 64 + j * 16 + lm) * PK + q * 8];
#pragma unroll
    for (int i = 0; i < 8; ++i)
#pragma unroll
      for (int j = 0; j < 4; ++j)
        acc[i][j] = __builtin_amdgcn_mfma_f32_16x16x32_bf16(af[i], bf[j], acc[i][j], 0, 0, 0);
  }

  // ---- partial store: tile position g, kt-contiguous ----
  {
    const int g = (bb * 2 + mt) * 2 + nt;
    float* Mp = Mout + ((size_t)g * NS + kt) * (size_t)(TM * TN);
#pragma unroll
    for (int i = 0; i < 8; ++i)
#pragma unroll
      for (int j = 0; j < 4; ++j)
#pragma unroll
        for (int r = 0; r < 4; ++r) {
          const int row = wm * 128 + i * 16 + q * 4 + r;   // local d'
          const int col = wn * 64 + j * 16 + lm;           // local d
          Mp[row * TN + col] = acc[i][j][r];
        }
    if (isB && mt == 0) {
      *(float4*)&vout[(size_t)((kt * NBATCH + bb) * 4 + trow) * DMODEL
                      + nt * TN + col4] = vacc4;
    }
  }
}

// ---------------------------------------------------------------------------
// Kernel 2 (fused reduce + gemm_c):
//   C[b][s][d] = sum_{d'} W[s][d'] * (sum_kt Mpart[...]) + bias[s]*v[b][d]
// 256 blocks (bb,mtc,ntc) x 256 thr. Per K-iter the M-staging sums the NS
// partials inline (fp32) before the bf16 convert -- W*(sum M) == the old
// reduce+gemm_c, with the 64 MB partial read absorbed into a kernel that was
// latency-bound anyway. The 8 mtc-readers of each Mpart region share
// blockIdx%8 == ntc -> same XCD -> 1 HBM fetch + 7 L2 hits per region.
// v-reduction (64 vpart rows) done by a 64-thread prologue into LDS.
// ---------------------------------------------------------------------------
template <int NS>
__global__ __launch_bounds__(256) void gemm_cr_kernel(
    const float* __restrict__ Wmat, const float* __restrict__ bias,
    const float* __restrict__ Mpart, const float* __restrict__ vpart,
    float* __restrict__ out)
{
  __shared__ short Wl[64 * PKC];     // 5 KB
  __shared__ short Ml[64 * PKC];     // 5 KB
  __shared__ float4 vred[4][16];     // 1 KB

  const int blk = blockIdx.x;          // grid = 4 * 8 * 8 = 256
  const int ntc = blk & 7;
  const int mtc = (blk >> 3) & 7;
  const int bb  = blk >> 6;

  const int tid  = threadIdx.x;
  const int wv   = tid >> 6;
  const int lane = tid & 63;
  const int lm   = lane & 15, q = lane >> 4;

  // ---- prologue: vl[d] = sum over NS*4 vpart rows for this batch ----
  if (tid < 64) {
    const int rg = tid >> 4, cg = tid & 15;
    const int dcol = ntc * 64 + cg * 4;
    float4 s = {0.f, 0.f, 0.f, 0.f};
#pragma unroll
    for (int i = 0; i < NS; ++i) {            // NS rows per thread
      const int ktv  = rg * (NS / 4) + (i >> 2);
      const int trow = i & 3;
      const int row  = (ktv * NBATCH + bb) * 4 + trow;
      const float4 v = *(const float4*)&vpart[(size_t)row * DMODEL + dcol];
      s.x += v.x; s.y += v.y; s.z += v.z; s.w += v.w;
    }
    vred[rg][cg] = s;
  }
  __syncthreads();
  if (tid < 16) {
    float4 a = vred[0][tid], b = vred[1][tid], c = vred[2][tid], d = vred[3][tid];
    a.x += b.x + c.x + d.x; a.y += b.y + c.y + d.y;
    a.z += b.z + c.z + d.z; a.w += b.w + c.w + d.w;
    vred[0][tid] = a;                       // final v for these 64 cols
  }
  // (covered by the K-loop's first __syncthreads before any re-read)

  facc acc[4];
#pragma unroll
  for (int j = 0; j < 4; ++j) acc[j] = (facc){0.f, 0.f, 0.f, 0.f};

  const int mrow2  = (tid >> 4) * 2;          // 0..30 (d'-row pair in K-tile)
  const int mcolg  = (tid & 15) * 4;          // 0..60 (local d col)
  const int ntq    = ntc >> 2;                // 256-wide partial nt
  const int colin  = (ntc & 3) * 64 + mcolg;  // col within 256-wide tile
  const int warow  = tid & 63;
  const int wahalf = (tid >> 6) * 8;
  constexpr size_t TILESZ = (size_t)TM * TN;  // 65536

  for (int k0 = 0; k0 < DMODEL; k0 += 32) {
    // ---- M stage + kt-sum (all 256 threads: 2 rows x 4 cols x NS) ----
    const int mt = k0 >> 8;
    const size_t gbase = ((size_t)((bb * 2 + mt) * 2 + ntq) * NS) * TILESZ
                       + (size_t)((k0 & 255) + mrow2) * TN + colin;
    float4 s0 = {0.f, 0.f, 0.f, 0.f}, s1 = {0.f, 0.f, 0.f, 0.f};
#pragma unroll
    for (int ktv = 0; ktv < NS; ++ktv) {
      const float4 a = *(const float4*)&Mpart[gbase + (size_t)ktv * TILESZ];
      const float4 b = *(const float4*)&Mpart[gbase + (size_t)ktv * TILESZ + TN];
      s0.x += a.x; s0.y += a.y; s0.z += a.z; s0.w += a.w;
      s1.x += b.x; s1.y += b.y; s1.z += b.z; s1.w += b.w;
    }
    // ---- W stage (all 256 threads: 1 row x 8 k) ----
    const float* wp = &Wmat[(size_t)(mtc * 64 + warow) * DMODEL + k0 + wahalf];
    const float4 w0 = *(const float4*)wp;
    const float4 w1 = *(const float4*)(wp + 4);

    __syncthreads();   // previous iteration's frag reads done
#pragma unroll
    for (int c = 0; c < 4; ++c) {
      const unsigned pv = pk2(selc(s0, c), selc(s1, c));
      *(unsigned*)&Ml[(mcolg + c) * PKC + mrow2] = pv;   // col-major, row-pair
    }
    {
      uint4 wpk;
      wpk.x = pk2(w0.x, w0.y); wpk.y = pk2(w0.z, w0.w);
      wpk.z = pk2(w1.x, w1.y); wpk.w = pk2(w1.z, w1.w);
      *(uint4*)&Wl[warow * PKC + wahalf] = wpk;
    }
    __syncthreads();

    // ---- frags + MFMA (wave wv: s-rows wv*16..+16) ----
    bfrag af = *(const bfrag*)&Wl[(wv * 16 + lm) * PKC + q * 8];
    bfrag bf[4];
#pragma unroll
    for (int j = 0; j < 4; ++j)
      bf[j] = *(const bfrag*)&Ml[(j * 16 + lm) * PKC + q * 8];
#pragma unroll
    for (int j = 0; j < 4; ++j)
      acc[j] = __builtin_amdgcn_mfma_f32_16x16x32_bf16(af, bf[j], acc[j], 0, 0, 0);
  }

  // ---- epilogue: C = acc + bias[s] * v[d] ----
  const float* vl = (const float*)&vred[0][0];
#pragma unroll
  for (int j = 0; j < 4; ++j) {
    const float vj = vl[j * 16 + lm];
#pragma unroll
    for (int r = 0; r < 4; ++r) {
      const int row = mtc * 64 + wv * 16 + q * 4 + r;   // s
      const int col = ntc * 64 + j * 16 + lm;           // d
      out[((size_t)bb * DMODEL + row) * DMODEL + col] =
          acc[j][r] + bias[row] * vj;
    }
  }
}

// ---------------------------------------------------------------------------
extern "C" void kernel_launch(void* const* d_in, const int* in_sizes, int n_in,
                              void* d_out, int out_size, void* d_ws, size_t ws_size,
                              hipStream_t stream) {
  const float* h    = (const float*)d_in[0];   // (4, 8192, 512) fp32
  const float* e    = (const float*)d_in[1];   // (4, 8192, 512) fp32
  const float* Wmat = (const float*)d_in[2];   // (512, 512) fp32
  const float* bias = (const float*)d_in[3];   // (512,) fp32
  float* out = (float*)d_out;                  // (4, 512, 512) fp32

  float* Mpart = (float*)d_ws;

  if (ws_size >= ws_need(16)) {
    float* vpart = Mpart + mpart_elems(16);
    gemm_m_kernel<16><<<NBATCH * 16 * 4, 512, 0, stream>>>(h, e, Mpart, vpart);
    gemm_cr_kernel<16><<<NBATCH * 64, 256, 0, stream>>>(Wmat, bias, Mpart, vpart, out);
  } else {
    float* vpart = Mpart + mpart_elems(8);
    gemm_m_kernel<8><<<NBATCH * 8 * 4, 512, 0, stream>>>(h, e, Mpart, vpart);
    gemm_cr_kernel<8><<<NBATCH * 64, 256, 0, stream>>>(Wmat, bias, Mpart, vpart, out);
  }
}

// Round 7
// 209.650 us; speedup vs baseline: 1.1520x; 1.1520x over previous
//
#include <hip/hip_runtime.h>
#include <hip/hip_bf16.h>
#include <math.h>
#include <stdint.h>

// Problem constants (fixed by the reference)
#define S_LEN  8192
#define DMODEL 512
#define NBATCH 4

// gemm_m tiling: 256x128 tile, 512 threads (8 waves as 4x2 of 64x64 subtiles).
// R7 = single change from the measured R4 kernel: atomic epilogue (measured
// killer: 66 MB fabric RMW, 1.9 TB/s) -> plain kt-contiguous partial stores
// (R5 layout). Keeps: R3 two-__syncthreads body (3.5 TB/s), R4 (bb,mt) XCD
// decode (FETCH 135 MB = input floor). C-phase reverts to the proven split:
// 1024-block streaming reduce + gemm_c (R6 showed fused C-phase at 1 blk/CU
// is latency-bound: 90 us, 467 GB/s, Occ 11%).
constexpr int TM = 256, TN = 128, BK = 32;
constexpr int PK = 40;                    // padded LDS row stride (shorts)

// gemm_c tiling
constexpr int CBK = 32;
constexpr int PKC = 40;

// Workspace layout (bytes):
//   Mred  @ 0          : 4 MB   (4 x 512 x 512 f32)
//   vws   @ 4MB        : 8 KB   (4 x 512 f32)
//   Mpart @ 4MB+8KB    : 32 positions x NS x 128 KB  (NS=16: 64 MB)
//   vpart @ after Mpart: NS*NBATCH rows x 2 KB
constexpr size_t MRED_OFF  = 0;
constexpr size_t VWS_OFF   = (size_t)NBATCH * DMODEL * DMODEL * 4;          // 4 MB
constexpr size_t MPART_OFF = VWS_OFF + (size_t)NBATCH * DMODEL * 4;         // +8 KB

__host__ __device__ constexpr size_t mpart_elems(int ns) {
  return (size_t)NBATCH * ns * 8 * (TM * TN);
}
__host__ __device__ constexpr size_t vpart_elems(int ns) {
  return (size_t)ns * NBATCH * DMODEL;
}
__host__ __device__ constexpr size_t ws_need(int ns) {
  return MPART_OFF + (mpart_elems(ns) + vpart_elems(ns)) * 4;   // ~68.3 MB @ NS=16
}

typedef short bfrag  __attribute__((ext_vector_type(8)));   // 8 bf16 (4 VGPRs)
typedef float facc   __attribute__((ext_vector_type(4)));   // 4 fp32 acc

__device__ __forceinline__ unsigned pk2(float a, float b) {
  __hip_bfloat162 t = __float22bfloat162_rn(make_float2(a, b));  // v_cvt_pk_bf16_f32
  union { __hip_bfloat162 h; unsigned u; } cc; cc.h = t; return cc.u;
}

__device__ __forceinline__ void atomAddF(float* p, float v) {
  unsafeAtomicAdd(p, v);
}

__device__ __forceinline__ float selc(const float4& v, int c) {
  return c == 0 ? v.x : c == 1 ? v.y : c == 2 ? v.z : v.w;
}

// ---------------------------------------------------------------------------
// Kernel 1: partial M[b][d'][d] = sum_{t in chunk} w_t h[b][t][d'] e[b][t][d]
// R4 body verbatim (two-__syncthreads, single-buffer LDS, register prefetch,
// packed bf16 convert). XCD decode: xcd=(bb,mt), slot=(kt,nt): h-panels
// shared 4x in-XCD (R4: FETCH 135 MB). Epilogue: plain partial stores,
// kt-contiguous per position g (R5 layout, streamed by reduce).
// ---------------------------------------------------------------------------
template <int NS, bool ATOMIC>
__global__ __launch_bounds__(512, 2) void gemm_m_kernel(
    const float* __restrict__ h, const float* __restrict__ e,
    float* __restrict__ Mout, float* __restrict__ vout)
{
  __shared__ short Al[TM * PK];   // 20 KB
  __shared__ short Bl[TN * PK];   // 10 KB

  constexpr int KCH = S_LEN / NS;          // 512 for NS=16

  // XCD-grouped decode (dispatcher round-robins blockIdx%8 across XCDs)
  const int sidx = blockIdx.x;
  const int xcd  = sidx & 7;
  const int slot = sidx >> 3;              // 0..63
  const int bb   = xcd >> 1;
  const int mt   = xcd & 1;
  const int kt   = slot & (NS - 1);
  const int nt   = slot / NS;              // 0..3

  const int tid  = threadIdx.x;
  const bool isB = (tid >= 256);       // wave-uniform (waves 4..7)
  const int hid  = tid & 255;
  const int colA = (hid >> 2) * 4;     // A: 0..252
  const int trA  = hid & 3;            // A: t-rows trA*8 .. +8
  const int colB = (hid >> 3) * 4;     // B: 0..124
  const int trB  = hid & 7;            // B: t-rows trB*4 .. +4

  const int wv   = tid >> 6;           // 8 waves -> 4x2 of 64x64 subtiles
  const int wm   = wv >> 1;            // 0..3 (row quarter)
  const int wn   = wv & 1;             // 0..1 (col half)
  const int lane = tid & 63;
  const int lm   = lane & 15, q = lane >> 4;

  const float* src = isB
      ? e + (size_t)bb * S_LEN * DMODEL + nt * TN + colB
      : h + (size_t)bb * S_LEN * DMODEL + mt * TM + colA;
  short* ldst = isB ? (Bl + colB * PK + trB * 4)
                    : (Al + colA * PK + trA * 8);
  const int tr0 = isB ? trB * 4 : trA * 8;   // first t-row this thread stages

  facc acc[4][4];
#pragma unroll
  for (int i = 0; i < 4; ++i)
#pragma unroll
    for (int j = 0; j < 4; ++j) acc[i][j] = (facc){0.f, 0.f, 0.f, 0.f};

  const float lnA = -(float)M_PI / (float)S_LEN;   // log(alpha), negative
  const int tstart = kt * KCH, tend = tstart + KCH;

  float wbase = __expf(lnA * (float)(S_LEN - 1 - tstart - trB * 4));
  const float stepw = __expf(-lnA * (float)BK);    // alpha^(-32)
  float cr[4];
#pragma unroll
  for (int r = 0; r < 4; ++r)
    cr[r] = __expf(-lnA * (float)r);               // alpha^(-r)

  float4 vacc4 = {0.f, 0.f, 0.f, 0.f};

  // ---- preload iter 0 ----
  float4 cur[8];
  {
    const float* p0 = src + (size_t)(tstart + tr0) * DMODEL;
    if (!isB) {
#pragma unroll
      for (int r = 0; r < 8; ++r) cur[r] = *(const float4*)(p0 + (size_t)r * DMODEL);
    } else {
#pragma unroll
      for (int r = 0; r < 4; ++r) cur[r] = *(const float4*)(p0 + (size_t)r * DMODEL);
    }
  }

  for (int t0 = tstart; t0 < tend; t0 += BK) {
    // ---- scale (B only) + v accumulate ----
    if (isB) {
#pragma unroll
      for (int r = 0; r < 4; ++r) {
        const float w = wbase * cr[r];
        cur[r].x *= w; cur[r].y *= w; cur[r].z *= w; cur[r].w *= w;
      }
      if (mt == 0) {
#pragma unroll
        for (int r = 0; r < 4; ++r) {
          vacc4.x += cur[r].x; vacc4.y += cur[r].y;
          vacc4.z += cur[r].z; vacc4.w += cur[r].w;
        }
      }
      wbase *= stepw;
    }

    // ---- packed bf16 convert + register transpose (frees cur) ----
    uint4 pk[4];
    if (!isB) {
#pragma unroll
      for (int c = 0; c < 4; ++c) {
        pk[c].x = pk2(selc(cur[0], c), selc(cur[1], c));
        pk[c].y = pk2(selc(cur[2], c), selc(cur[3], c));
        pk[c].z = pk2(selc(cur[4], c), selc(cur[5], c));
        pk[c].w = pk2(selc(cur[6], c), selc(cur[7], c));
      }
    } else {
#pragma unroll
      for (int c = 0; c < 4; ++c) {
        pk[c].x = pk2(selc(cur[0], c), selc(cur[1], c));
        pk[c].y = pk2(selc(cur[2], c), selc(cur[3], c));
      }
    }

    // ---- issue next tile's loads (prefetch distance ~= one iteration) ----
    if (t0 + BK < tend) {
      const float* p0 = src + (size_t)(t0 + BK + tr0) * DMODEL;
      if (!isB) {
#pragma unroll
        for (int r = 0; r < 8; ++r) cur[r] = *(const float4*)(p0 + (size_t)r * DMODEL);
      } else {
#pragma unroll
        for (int r = 0; r < 4; ++r) cur[r] = *(const float4*)(p0 + (size_t)r * DMODEL);
      }
    }

    __syncthreads();   // previous iteration's frag reads done
    if (!isB) {
#pragma unroll
      for (int c = 0; c < 4; ++c)
        *(uint4*)(ldst + c * PK) = pk[c];
    } else {
#pragma unroll
      for (int c = 0; c < 4; ++c) {
        uint2 t2; t2.x = pk[c].x; t2.y = pk[c].y;
        *(uint2*)(ldst + c * PK) = t2;
      }
    }
    __syncthreads();

    bfrag af[4], bf[4];
#pragma unroll
    for (int i = 0; i < 4; ++i)
      af[i] = *(const bfrag*)&Al[(wm * 64 + i * 16 + lm) * PK + q * 8];
#pragma unroll
    for (int j = 0; j < 4; ++j)
      bf[j] = *(const bfrag*)&Bl[(wn * 64 + j * 16 + lm) * PK + q * 8];
#pragma unroll
    for (int i = 0; i < 4; ++i)
#pragma unroll
      for (int j = 0; j < 4; ++j)
        acc[i][j] = __builtin_amdgcn_mfma_f32_16x16x32_bf16(af[i], bf[j], acc[i][j], 0, 0, 0);
  }

  // ---- v reduction across the 8 t-row groups (lane bits 0..2 of B waves) ----
  if (isB && mt == 0) {
#pragma unroll
    for (int m = 1; m <= 4; m <<= 1) {
      vacc4.x += __shfl_xor(vacc4.x, m);
      vacc4.y += __shfl_xor(vacc4.y, m);
      vacc4.z += __shfl_xor(vacc4.z, m);
      vacc4.w += __shfl_xor(vacc4.w, m);
    }
  }

  if (ATOMIC) {
    float* Mb = Mout + (size_t)bb * DMODEL * DMODEL;
#pragma unroll
    for (int i = 0; i < 4; ++i)
#pragma unroll
      for (int j = 0; j < 4; ++j)
#pragma unroll
        for (int r = 0; r < 4; ++r) {
          const int row = mt * TM + wm * 64 + i * 16 + q * 4 + r;
          const int col = nt * TN + wn * 64 + j * 16 + lm;
          atomAddF(&Mb[(size_t)row * DMODEL + col], acc[i][j][r]);
        }
    if (isB && mt == 0 && (lane & 7) == 0) {
      float* vp = &vout[bb * DMODEL + nt * TN + colB];
      atomAddF(vp + 0, vacc4.x); atomAddF(vp + 1, vacc4.y);
      atomAddF(vp + 2, vacc4.z); atomAddF(vp + 3, vacc4.w);
    }
  } else {
    // plain partial stores: position g, kt-contiguous (R5-proven layout)
    const int g = (bb * 2 + mt) * 4 + nt;
    float* Mp = Mout + ((size_t)g * NS + kt) * (size_t)(TM * TN);
#pragma unroll
    for (int i = 0; i < 4; ++i)
#pragma unroll
      for (int j = 0; j < 4; ++j)
#pragma unroll
        for (int r = 0; r < 4; ++r) {
          const int row = wm * 64 + i * 16 + q * 4 + r;    // local d'
          const int col = wn * 64 + j * 16 + lm;           // local d
          Mp[row * TN + col] = acc[i][j][r];
        }
    if (isB && mt == 0 && (lane & 7) == 0) {
      *(float4*)&vout[(size_t)(kt * NBATCH + bb) * DMODEL + nt * TN + colB] = vacc4;
    }
  }
}

// ---------------------------------------------------------------------------
// Reduce: Mred = sum_kt Mpart; vws = sum_kt vpart.  1024 blocks x 256 thr
// (streaming, 4 blocks/CU). Partial layout: g=(bb*2+mt)*4+nt, kt-contiguous.
// ---------------------------------------------------------------------------
template <int NS>
__global__ __launch_bounds__(256) void reduce_kernel(
    const float* __restrict__ Mpart, const float* __restrict__ vpart,
    float* __restrict__ Mred, float* __restrict__ vws)
{
  const int gid = blockIdx.x * 256 + threadIdx.x;    // one float4 each
  const int bb   = gid >> 16;            // 65536 float4 per batch
  const int rem  = gid & 65535;
  const int R    = rem >> 7;             // output row 0..511
  const int c128 = rem & 127;            // float4 col 0..127

  const int mt = R >> 8, r = R & 255;
  const int nt = c128 >> 5;
  const int cin = (c128 & 31) * 4;       // col within 128-wide tile

  const size_t tilesz = (size_t)TM * TN; // 32768
  const size_t base = ((size_t)((bb * 2 + mt) * 4 + nt) * NS) * tilesz
                    + (size_t)r * TN + cin;
  float4 s = {0.f, 0.f, 0.f, 0.f};
#pragma unroll
  for (int kt = 0; kt < NS; ++kt) {
    const float4 v = *(const float4*)&Mpart[base + (size_t)kt * tilesz];
    s.x += v.x; s.y += v.y; s.z += v.z; s.w += v.w;
  }
  *(float4*)&Mred[((size_t)bb * DMODEL + R) * DMODEL + c128 * 4] = s;

  if (gid < (NBATCH * DMODEL / 4)) {     // 512 threads: v reduction
    const int vb = gid >> 7;
    const int vc = (gid & 127) * 4;
    float4 vs = {0.f, 0.f, 0.f, 0.f};
#pragma unroll
    for (int kt = 0; kt < NS; ++kt) {
      const float4 v = *(const float4*)&vpart[(size_t)(kt * NBATCH + vb) * DMODEL + vc];
      vs.x += v.x; vs.y += v.y; vs.z += v.z; vs.w += v.w;
    }
    *(float4*)&vws[vb * DMODEL + vc] = vs;
  }
}

// ---------------------------------------------------------------------------
// Kernel 3: C[b][s][d] = sum_{d'} W[s][d'] Mred[b][d'][d] + bias[s]*v[b][d]
// 64x64 tiles, K=512, 16 pipelined iters, plain stores. (R0/R5 verbatim.)
// ---------------------------------------------------------------------------
__global__ __launch_bounds__(256) void gemm_c_kernel(
    const float* __restrict__ Wmat, const float* __restrict__ bias,
    const float* __restrict__ Mred, const float* __restrict__ vws,
    float* __restrict__ out)
{
  __shared__ short Wl[64 * PKC];
  __shared__ short Ml[64 * PKC];

  const int blk = blockIdx.x;          // grid = 4 * 8 * 8 = 256
  const int ntc = blk & 7;
  const int mtc = (blk >> 3) & 7;
  const int bb  = blk >> 6;

  const int tid  = threadIdx.x;
  const bool isM = (tid >= 128);
  const int hid  = tid & 127;
  const int arow = hid & 63;           // W-half
  const int ahalf = (hid >> 6) * 16;
  const int mcol4 = (hid & 15) * 4;    // M-half
  const int mrow4 = (hid >> 4) * 4;

  const int wv   = tid >> 6;
  const int lane = tid & 63;
  const int lm   = lane & 15, q = lane >> 4;

  const float* Mb = Mred + (size_t)bb * DMODEL * DMODEL;

  facc acc[4];
#pragma unroll
  for (int j = 0; j < 4; ++j) acc[j] = (facc){0.f, 0.f, 0.f, 0.f};

  float4 cur[4];
  if (!isM) {
    const float* p = &Wmat[(size_t)(mtc * 64 + arow) * DMODEL + ahalf];
#pragma unroll
    for (int r = 0; r < 4; ++r) cur[r] = *(const float4*)(p + r * 4);
  } else {
    const float* p = Mb + (size_t)mrow4 * DMODEL + ntc * 64 + mcol4;
#pragma unroll
    for (int r = 0; r < 4; ++r) cur[r] = *(const float4*)(p + (size_t)r * DMODEL);
  }

  for (int k0 = 0; k0 < DMODEL; k0 += CBK) {
    uint4 pw0, pw1;
    uint2 pm[4];
    if (!isM) {
      pw0.x = pk2(cur[0].x, cur[0].y); pw0.y = pk2(cur[0].z, cur[0].w);
      pw0.z = pk2(cur[1].x, cur[1].y); pw0.w = pk2(cur[1].z, cur[1].w);
      pw1.x = pk2(cur[2].x, cur[2].y); pw1.y = pk2(cur[2].z, cur[2].w);
      pw1.z = pk2(cur[3].x, cur[3].y); pw1.w = pk2(cur[3].z, cur[3].w);
    } else {
#pragma unroll
      for (int c = 0; c < 4; ++c) {
        pm[c].x = pk2(selc(cur[0], c), selc(cur[1], c));
        pm[c].y = pk2(selc(cur[2], c), selc(cur[3], c));
      }
    }

    if (k0 + CBK < DMODEL) {
      if (!isM) {
        const float* p = &Wmat[(size_t)(mtc * 64 + arow) * DMODEL + k0 + CBK + ahalf];
#pragma unroll
        for (int r = 0; r < 4; ++r) cur[r] = *(const float4*)(p + r * 4);
      } else {
        const float* p = Mb + (size_t)(k0 + CBK + mrow4) * DMODEL + ntc * 64 + mcol4;
#pragma unroll
        for (int r = 0; r < 4; ++r) cur[r] = *(const float4*)(p + (size_t)r * DMODEL);
      }
    }

    __syncthreads();
    if (!isM) {
      *(uint4*)&Wl[arow * PKC + ahalf]     = pw0;
      *(uint4*)&Wl[arow * PKC + ahalf + 8] = pw1;
    } else {
#pragma unroll
      for (int c = 0; c < 4; ++c)
        *(uint2*)&Ml[(mcol4 + c) * PKC + mrow4] = pm[c];
    }
    __syncthreads();

    bfrag af, bf[4];
    af = *(const bfrag*)&Wl[(wv * 16 + lm) * PKC + q * 8];
#pragma unroll
    for (int j = 0; j < 4; ++j)
      bf[j] = *(const bfrag*)&Ml[(j * 16 + lm) * PKC + q * 8];
#pragma unroll
    for (int j = 0; j < 4; ++j)
      acc[j] = __builtin_amdgcn_mfma_f32_16x16x32_bf16(af, bf[j], acc[j], 0, 0, 0);
  }

#pragma unroll
  for (int j = 0; j < 4; ++j)
#pragma unroll
    for (int r = 0; r < 4; ++r) {
      const int row = mtc * 64 + wv * 16 + q * 4 + r;   // s
      const int col = ntc * 64 + j * 16 + lm;           // d
      out[((size_t)bb * DMODEL + row) * DMODEL + col] =
          acc[j][r] + bias[row] * vws[bb * DMODEL + col];
    }
}

// ---------------------------------------------------------------------------
extern "C" void kernel_launch(void* const* d_in, const int* in_sizes, int n_in,
                              void* d_out, int out_size, void* d_ws, size_t ws_size,
                              hipStream_t stream) {
  const float* h    = (const float*)d_in[0];   // (4, 8192, 512) fp32
  const float* e    = (const float*)d_in[1];   // (4, 8192, 512) fp32
  const float* Wmat = (const float*)d_in[2];   // (512, 512) fp32
  const float* bias = (const float*)d_in[3];   // (512,) fp32
  float* out = (float*)d_out;                  // (4, 512, 512) fp32

  float* Mred  = (float*)((char*)d_ws + MRED_OFF);
  float* vws   = (float*)((char*)d_ws + VWS_OFF);
  float* Mpart = (float*)((char*)d_ws + MPART_OFF);

  constexpr int NS = 16;                       // grid 512 = 2 blocks/CU
  if (ws_size >= ws_need(NS)) {
    float* vpart = Mpart + mpart_elems(NS);
    gemm_m_kernel<NS, false><<<NBATCH * NS * 8, 512, 0, stream>>>(h, e, Mpart, vpart);
    reduce_kernel<NS><<<1024, 256, 0, stream>>>(Mpart, vpart, Mred, vws);
  } else {
    hipMemsetAsync(d_ws, 0, VWS_OFF + (size_t)NBATCH * DMODEL * 4, stream);
    gemm_m_kernel<NS, true><<<NBATCH * NS * 8, 512, 0, stream>>>(h, e, Mred, vws);
  }
  gemm_c_kernel<<<NBATCH * 64, 256, 0, stream>>>(Wmat, bias, Mred, vws, out);
}

// Round 8
// 190.560 us; speedup vs baseline: 1.2674x; 1.1002x over previous
//
#include <hip/hip_runtime.h>
#include <hip/hip_bf16.h>
#include <math.h>
#include <stdint.h>

// Problem constants (fixed by the reference)
#define S_LEN  8192
#define DMODEL 512
#define NBATCH 4

// R8 = R0 config (best measured: gemm_m 63 us, total 197.8) + three
// independently-readable changes:
//   1. bf16 row-pair partials: Mpart 64->32 MB (acc r-pairs are adjacent
//      ROWS of one column -> in-thread pk2, no cross-lane). WRITE 66->34,
//      reduce traffic 132->37 MB.
//   2. __builtin_nontemporal_load on gemm_m's streaming h/e reads: probe of
//      the ~8 B/cyc/CU logical-delivery wall seen in ALL 7 prior variants
//      (L1 MSHR hypothesis). Readout: FETCH stable + dur down = confirmed;
//      FETCH ballooned = nt killed L2/L3 reuse -> revert next round.
//   3. R1-proven bijective XCD swizzle (FETCH 131->71 MB) on the R0 body
//      (this combination ran and passed in R6).
// Everything else R0 verbatim: 256x256 tile, two-__syncthreads loop, grid
// 256, NS=16, fp32 Mred, gemm_c untouched. Register lesson (R7 post-mortem):
// acc is AGPR, total = VGPR+AGPR ~244/wave -> 1 block/CU is structural here.
constexpr int TM = 256, TN = 256, BK = 32;
constexpr int PK = 40;                    // padded LDS row stride (shorts)

// gemm_c tiling
constexpr int CBK = 32;
constexpr int PKC = 40;

// Workspace layout (bytes):
//   Mred  @ 0          : 4 MB   (4 x 512 x 512 f32)
//   vws   @ 4MB        : 8 KB   (4 x 512 f32)
//   Mpart @ 4MB+8KB    : NBATCH*NS*4 tiles x 128 KB bf16-pairs (NS=16: 32 MB)
//   vpart @ after Mpart: NS*NBATCH*4 rows x 2 KB f32
constexpr size_t MRED_OFF  = 0;
constexpr size_t VWS_OFF   = (size_t)NBATCH * DMODEL * DMODEL * 4;          // 4 MB
constexpr size_t MPART_OFF = VWS_OFF + (size_t)NBATCH * DMODEL * 4;         // +8 KB

__host__ __device__ constexpr size_t mpart_uints(int ns) {
  return (size_t)NBATCH * ns * 4 * (TM * TN / 2);   // uint(=2 bf16) elems
}
__host__ __device__ constexpr size_t vpart_elems(int ns) {
  return (size_t)ns * NBATCH * 4 * DMODEL;
}
__host__ __device__ constexpr size_t ws_need(int ns) {
  return MPART_OFF + (mpart_uints(ns) + vpart_elems(ns)) * 4;  // ~36.6 MB @ NS=16
}

typedef short bfrag  __attribute__((ext_vector_type(8)));   // 8 bf16 (4 VGPRs)
typedef float facc   __attribute__((ext_vector_type(4)));   // 4 fp32 acc
typedef float f32x4v __attribute__((ext_vector_type(4)));

__device__ __forceinline__ unsigned pk2(float a, float b) {
  __hip_bfloat162 t = __float22bfloat162_rn(make_float2(a, b));  // v_cvt_pk_bf16_f32
  union { __hip_bfloat162 h; unsigned u; } cc; cc.h = t; return cc.u;
}

__device__ __forceinline__ float selc(const float4& v, int c) {
  return c == 0 ? v.x : c == 1 ? v.y : c == 2 ? v.z : v.w;
}

// non-temporal float4 load (global_load_dwordx4 ... nt)
__device__ __forceinline__ float4 ldnt4(const float* p) {
  f32x4v v = __builtin_nontemporal_load((const f32x4v*)p);
  float4 r; r.x = v.x; r.y = v.y; r.z = v.z; r.w = v.w; return r;
}

// bf16(low/high half of uint) -> f32
__device__ __forceinline__ float bflo(unsigned u) {
  union { unsigned u; float f; } c; c.u = u << 16; return c.f;
}
__device__ __forceinline__ float bfhi(unsigned u) {
  union { unsigned u; float f; } c; c.u = u & 0xffff0000u; return c.f;
}

// ---------------------------------------------------------------------------
// Kernel 1: partial M[b][d'][d] = sum_{t in chunk} w_t h[b][t][d'] e[b][t][d]
// R0 body verbatim: 256x256 tile, 512 thr, waves 0-3 stage A(h), 4-7 stage
// B(e), register prefetch, packed bf16 convert, two __syncthreads per iter.
// Changes: (a) bijective XCD swizzle, (b) nt input loads, (c) bf16 row-pair
// partial stores: uint at [row>>1][col] = pk2(acc[r even], acc[r odd]).
// ---------------------------------------------------------------------------
template <int NS>
__global__ __launch_bounds__(512, 2) void gemm_m_kernel(
    const float* __restrict__ h, const float* __restrict__ e,
    unsigned* __restrict__ Mout, float* __restrict__ vout)
{
  __shared__ short Al[TM * PK];   // 20 KB
  __shared__ short Bl[TN * PK];   // 20 KB

  constexpr int KCH = S_LEN / NS;

  // bijective XCD swizzle (grid % 8 == 0): XCD x gets logical [x*32, +32)
  // = one bb, contiguous kt-range, all 4 (mt,nt) -> full panel reuse in-XCD.
  const int sidx = blockIdx.x;
  const int blk  = (sidx & 7) * (int)(gridDim.x >> 3) + (sidx >> 3);

  const int nt  = blk & 1;
  const int mt  = (blk >> 1) & 1;
  const int kt  = (blk >> 2) % NS;
  const int bb  = blk / (4 * NS);

  const int tid   = threadIdx.x;
  const bool isB  = (tid >= 256);      // wave-uniform (waves 4..7)
  const int hid   = tid & 255;
  const int col4  = (hid >> 2) * 4;    // 0..252 within the 256-wide tile
  const int trow  = hid & 3;           // t-rows trow*8 .. trow*8+7

  const int wv   = tid >> 6;           // 8 waves -> 2x4 of 128x64 subtiles
  const int wm   = wv >> 2;            // 0..1 (row half)
  const int wn   = wv & 3;             // 0..3 (col quarter)
  const int lane = tid & 63;
  const int lm   = lane & 15, q = lane >> 4;

  const float* src = (isB ? e : h) + (size_t)bb * S_LEN * DMODEL
                   + (isB ? nt * TN : mt * TM) + col4;
  short* ldst = (isB ? Bl : Al) + col4 * PK + trow * 8;

  facc acc[8][4];
#pragma unroll
  for (int i = 0; i < 8; ++i)
#pragma unroll
    for (int j = 0; j < 4; ++j) acc[i][j] = (facc){0.f, 0.f, 0.f, 0.f};

  const float lnA = -(float)M_PI / (float)S_LEN;   // log(alpha), negative
  const int tstart = kt * KCH, tend = tstart + KCH;

  float wbase = __expf(lnA * (float)(S_LEN - 1 - tstart - trow * 8));
  const float stepw = __expf(-lnA * (float)BK);    // alpha^(-32)
  float cr[8];
#pragma unroll
  for (int r = 0; r < 8; ++r)
    cr[r] = __expf(-lnA * (float)r);               // alpha^(-r)

  float4 vacc4 = {0.f, 0.f, 0.f, 0.f};

  // ---- preload iter 0 (nt) ----
  float4 cur[8];
  {
    const float* p = src + (size_t)(tstart + trow * 8) * DMODEL;
#pragma unroll
    for (int r = 0; r < 8; ++r) cur[r] = ldnt4(p + (size_t)r * DMODEL);
  }

  for (int t0 = tstart; t0 < tend; t0 += BK) {
    // ---- scale (B only) + v accumulate ----
    if (isB) {
#pragma unroll
      for (int r = 0; r < 8; ++r) {
        const float w = wbase * cr[r];
        cur[r].x *= w; cur[r].y *= w; cur[r].z *= w; cur[r].w *= w;
      }
      if (mt == 0) {
#pragma unroll
        for (int r = 0; r < 8; ++r) {
          vacc4.x += cur[r].x; vacc4.y += cur[r].y;
          vacc4.z += cur[r].z; vacc4.w += cur[r].w;
        }
      }
    }
    wbase *= stepw;

    // ---- packed bf16 convert + register transpose (frees cur) ----
    uint4 pk[4];
#pragma unroll
    for (int c = 0; c < 4; ++c) {
      pk[c].x = pk2(selc(cur[0], c), selc(cur[1], c));
      pk[c].y = pk2(selc(cur[2], c), selc(cur[3], c));
      pk[c].z = pk2(selc(cur[4], c), selc(cur[5], c));
      pk[c].w = pk2(selc(cur[6], c), selc(cur[7], c));
    }

    // ---- issue next tile's loads (prefetch distance ~= one iteration) ----
    if (t0 + BK < tend) {
      const float* p = src + (size_t)(t0 + BK + trow * 8) * DMODEL;
#pragma unroll
      for (int r = 0; r < 8; ++r) cur[r] = ldnt4(p + (size_t)r * DMODEL);
    }

    __syncthreads();   // previous iteration's frag reads done
#pragma unroll
    for (int c = 0; c < 4; ++c)
      *(uint4*)(ldst + c * PK) = pk[c];
    __syncthreads();

    bfrag af[8], bf[4];
#pragma unroll
    for (int i = 0; i < 8; ++i)
      af[i] = *(const bfrag*)&Al[(wm * 128 + i * 16 + lm) * PK + q * 8];
#pragma unroll
    for (int j = 0; j < 4; ++j)
      bf[j] = *(const bfrag*)&Bl[(wn * 64 + j * 16 + lm) * PK + q * 8];
#pragma unroll
    for (int i = 0; i < 8; ++i)
#pragma unroll
      for (int j = 0; j < 4; ++j)
        acc[i][j] = __builtin_amdgcn_mfma_f32_16x16x32_bf16(af[i], bf[j], acc[i][j], 0, 0, 0);
  }

  // ---- bf16 row-pair partial store: uint[row>>1][col] = (lo=r_even, hi=r_odd)
  {
    unsigned* Mp = Mout + (size_t)blk * (TM * TN / 2);
#pragma unroll
    for (int i = 0; i < 8; ++i)
#pragma unroll
      for (int j = 0; j < 4; ++j) {
        const int pbase = wm * 64 + i * 8 + q * 2;       // (row>>1) base
        const int col   = wn * 64 + j * 16 + lm;
        Mp[(pbase + 0) * TN + col] = pk2(acc[i][j][0], acc[i][j][1]);
        Mp[(pbase + 1) * TN + col] = pk2(acc[i][j][2], acc[i][j][3]);
      }
    if (isB && mt == 0) {
      *(float4*)&vout[(size_t)((kt * NBATCH + bb) * 4 + trow) * DMODEL
                      + nt * TN + col4] = vacc4;
    }
  }
}

// ---------------------------------------------------------------------------
// Reduce: Mred(f32) = sum_kt Mpart(bf16 pairs); vws = sum vpart.
// 512 blocks x 256 thr; each thread: one uint4 (4 cols x 2 rows) x NS.
// ---------------------------------------------------------------------------
template <int NS>
__global__ __launch_bounds__(256) void reduce_kernel(
    const unsigned* __restrict__ Mpart, const float* __restrict__ vpart,
    float* __restrict__ Mred, float* __restrict__ vws)
{
  const int gid = blockIdx.x * 256 + threadIdx.x;    // one uint4 each
  const int bb     = gid >> 15;          // 32768 uint4 per batch
  const int rem    = gid & 32767;
  const int tile   = rem >> 13;          // 4 tiles (mt*2+nt)
  const int within = rem & 8191;         // uint4 index inside tile

  const int pr  = within >> 6;           // pair-row 0..127
  const int c4  = (within & 63) * 4;     // col base (uint4-aligned)

  constexpr size_t TILESZ_U = (size_t)TM * TN / 2;   // 32768 uints
  const size_t base = ((size_t)(bb * NS) * 4 + tile) * TILESZ_U
                    + (size_t)pr * TN + c4;

  float4 s0 = {0.f, 0.f, 0.f, 0.f};      // even row
  float4 s1 = {0.f, 0.f, 0.f, 0.f};      // odd row
#pragma unroll
  for (int kt = 0; kt < NS; ++kt) {
    const uint4 v = *(const uint4*)&Mpart[base + (size_t)kt * 4 * TILESZ_U];
    s0.x += bflo(v.x); s1.x += bfhi(v.x);
    s0.y += bflo(v.y); s1.y += bfhi(v.y);
    s0.z += bflo(v.z); s1.z += bfhi(v.z);
    s0.w += bflo(v.w); s1.w += bfhi(v.w);
  }
  const int mt = tile >> 1, ntt = tile & 1;
  const int grow = mt * TM + pr * 2;
  const int gcol = ntt * TN + c4;
  float* outp = &Mred[(size_t)bb * DMODEL * DMODEL + (size_t)grow * DMODEL + gcol];
  *(float4*)outp            = s0;
  *(float4*)(outp + DMODEL) = s1;

  if (gid < (NBATCH * DMODEL / 4)) {     // 512 threads: v reduction
    const int vb = gid >> 7;
    const int vc = (gid & 127) * 4;
    float4 vs = {0.f, 0.f, 0.f, 0.f};
#pragma unroll
    for (int kt = 0; kt < NS; ++kt)
#pragma unroll
      for (int tr = 0; tr < 4; ++tr) {
        const float4 v = *(const float4*)&vpart[(size_t)((kt * NBATCH + vb) * 4 + tr) * DMODEL + vc];
        vs.x += v.x; vs.y += v.y; vs.z += v.z; vs.w += v.w;
      }
    *(float4*)&vws[vb * DMODEL + vc] = vs;
  }
}

// ---------------------------------------------------------------------------
// Kernel 3: C[b][s][d] = sum_{d'} W[s][d'] Mred[b][d'][d] + bias[s]*v[b][d]
// 64x64 tiles, K=512, 16 pipelined iters, plain stores. (R0 verbatim.)
// ---------------------------------------------------------------------------
__global__ __launch_bounds__(256) void gemm_c_kernel(
    const float* __restrict__ Wmat, const float* __restrict__ bias,
    const float* __restrict__ Mred, const float* __restrict__ vws,
    float* __restrict__ out)
{
  __shared__ short Wl[64 * PKC];
  __shared__ short Ml[64 * PKC];

  const int blk = blockIdx.x;          // grid = 4 * 8 * 8 = 256
  const int ntc = blk & 7;
  const int mtc = (blk >> 3) & 7;
  const int bb  = blk >> 6;

  const int tid  = threadIdx.x;
  const bool isM = (tid >= 128);
  const int hid  = tid & 127;
  const int arow = hid & 63;           // W-half
  const int ahalf = (hid >> 6) * 16;
  const int mcol4 = (hid & 15) * 4;    // M-half
  const int mrow4 = (hid >> 4) * 4;

  const int wv   = tid >> 6;
  const int lane = tid & 63;
  const int lm   = lane & 15, q = lane >> 4;

  const float* Mb = Mred + (size_t)bb * DMODEL * DMODEL;

  facc acc[4];
#pragma unroll
  for (int j = 0; j < 4; ++j) acc[j] = (facc){0.f, 0.f, 0.f, 0.f};

  float4 cur[4];
  if (!isM) {
    const float* p = &Wmat[(size_t)(mtc * 64 + arow) * DMODEL + ahalf];
#pragma unroll
    for (int r = 0; r < 4; ++r) cur[r] = *(const float4*)(p + r * 4);
  } else {
    const float* p = Mb + (size_t)mrow4 * DMODEL + ntc * 64 + mcol4;
#pragma unroll
    for (int r = 0; r < 4; ++r) cur[r] = *(const float4*)(p + (size_t)r * DMODEL);
  }

  for (int k0 = 0; k0 < DMODEL; k0 += CBK) {
    uint4 pw0, pw1;
    uint2 pm[4];
    if (!isM) {
      pw0.x = pk2(cur[0].x, cur[0].y); pw0.y = pk2(cur[0].z, cur[0].w);
      pw0.z = pk2(cur[1].x, cur[1].y); pw0.w = pk2(cur[1].z, cur[1].w);
      pw1.x = pk2(cur[2].x, cur[2].y); pw1.y = pk2(cur[2].z, cur[2].w);
      pw1.z = pk2(cur[3].x, cur[3].y); pw1.w = pk2(cur[3].z, cur[3].w);
    } else {
#pragma unroll
      for (int c = 0; c < 4; ++c) {
        pm[c].x = pk2(selc(cur[0], c), selc(cur[1], c));
        pm[c].y = pk2(selc(cur[2], c), selc(cur[3], c));
      }
    }

    if (k0 + CBK < DMODEL) {
      if (!isM) {
        const float* p = &Wmat[(size_t)(mtc * 64 + arow) * DMODEL + k0 + CBK + ahalf];
#pragma unroll
        for (int r = 0; r < 4; ++r) cur[r] = *(const float4*)(p + r * 4);
      } else {
        const float* p = Mb + (size_t)(k0 + CBK + mrow4) * DMODEL + ntc * 64 + mcol4;
#pragma unroll
        for (int r = 0; r < 4; ++r) cur[r] = *(const float4*)(p + (size_t)r * DMODEL);
      }
    }

    __syncthreads();
    if (!isM) {
      *(uint4*)&Wl[arow * PKC + ahalf]     = pw0;
      *(uint4*)&Wl[arow * PKC + ahalf + 8] = pw1;
    } else {
#pragma unroll
      for (int c = 0; c < 4; ++c)
        *(uint2*)&Ml[(mcol4 + c) * PKC + mrow4] = pm[c];
    }
    __syncthreads();

    bfrag af, bf[4];
    af = *(const bfrag*)&Wl[(wv * 16 + lm) * PKC + q * 8];
#pragma unroll
    for (int j = 0; j < 4; ++j)
      bf[j] = *(const bfrag*)&Ml[(j * 16 + lm) * PKC + q * 8];
#pragma unroll
    for (int j = 0; j < 4; ++j)
      acc[j] = __builtin_amdgcn_mfma_f32_16x16x32_bf16(af, bf[j], acc[j], 0, 0, 0);
  }

#pragma unroll
  for (int j = 0; j < 4; ++j)
#pragma unroll
    for (int r = 0; r < 4; ++r) {
      const int row = mtc * 64 + wv * 16 + q * 4 + r;   // s
      const int col = ntc * 64 + j * 16 + lm;           // d
      out[((size_t)bb * DMODEL + row) * DMODEL + col] =
          acc[j][r] + bias[row] * vws[bb * DMODEL + col];
    }
}

// ---------------------------------------------------------------------------
extern "C" void kernel_launch(void* const* d_in, const int* in_sizes, int n_in,
                              void* d_out, int out_size, void* d_ws, size_t ws_size,
                              hipStream_t stream) {
  const float* h    = (const float*)d_in[0];   // (4, 8192, 512) fp32
  const float* e    = (const float*)d_in[1];   // (4, 8192, 512) fp32
  const float* Wmat = (const float*)d_in[2];   // (512, 512) fp32
  const float* bias = (const float*)d_in[3];   // (512,) fp32
  float* out = (float*)d_out;                  // (4, 512, 512) fp32

  float*    Mred  = (float*)((char*)d_ws + MRED_OFF);
  float*    vws   = (float*)((char*)d_ws + VWS_OFF);
  unsigned* Mpart = (unsigned*)((char*)d_ws + MPART_OFF);

  constexpr int NS = 16;                       // grid 256 (R0 config)
  float* vpart = (float*)(Mpart + mpart_uints(NS));
  gemm_m_kernel<NS><<<NBATCH * NS * 4, 512, 0, stream>>>(h, e, Mpart, vpart);
  reduce_kernel<NS><<<512, 256, 0, stream>>>(Mpart, vpart, Mred, vws);
  gemm_c_kernel<<<NBATCH * 64, 256, 0, stream>>>(Wmat, bias, Mred, vws, out);
}

// Round 9
// 181.683 us; speedup vs baseline: 1.3293x; 1.0489x over previous
//
#include <hip/hip_runtime.h>
#include <hip/hip_bf16.h>
#include <math.h>
#include <stdint.h>

// Problem constants (fixed by the reference)
#define S_LEN  8192
#define DMODEL 512
#define NBATCH 4

// R9 = R8 (gemm_m UNTOUCHED: 46.9 us measured, at its logical-delivery
// roofline ~10.2 B/cyc/CU) + C-phase de-amplification:
//   - reduce writes bf16 row-pair Mredb (2 MB, was 16 MB fp32): WRITE -14MB.
//   - gemm_c reads Mredb: M logical traffic 128 MB -> 16 MB (the 8x mtc
//     amplification now moves bf16), and M-staging is pure uint4 loads ->
//     LDS scatter (row-pair format matches the LDS layout bit-for-bit,
//     conversion VALU deleted).
//   - nt loads on reduce's streaming Mpart.
// R8 lessons kept: bf16 row-pair partials (WRITE 66->33), nt input loads +
// bijective XCD swizzle (FETCH 131->76), launch_bounds(512,2), acc is AGPR
// (VGPR+AGPR ~244/wave -> 1 block/CU structural for the 256x256 tile).
constexpr int TM = 256, TN = 256, BK = 32;
constexpr int PK = 40;                    // padded LDS row stride (shorts)

// gemm_c tiling
constexpr int CBK = 32;
constexpr int PKC = 40;

// Workspace layout (bytes) — offsets identical to R8:
//   Mredb @ 0          : 2 MB used (4 MB reserved)  bf16 row-pairs
//   vws   @ 4MB        : 8 KB   (4 x 512 f32)
//   Mpart @ 4MB+8KB    : NBATCH*NS*4 tiles x 128 KB bf16-pairs (NS=16: 32 MB)
//   vpart @ after Mpart: NS*NBATCH*4 rows x 2 KB f32
constexpr size_t MRED_OFF  = 0;
constexpr size_t VWS_OFF   = (size_t)NBATCH * DMODEL * DMODEL * 4;          // 4 MB
constexpr size_t MPART_OFF = VWS_OFF + (size_t)NBATCH * DMODEL * 4;         // +8 KB

__host__ __device__ constexpr size_t mpart_uints(int ns) {
  return (size_t)NBATCH * ns * 4 * (TM * TN / 2);   // uint(=2 bf16) elems
}
__host__ __device__ constexpr size_t vpart_elems(int ns) {
  return (size_t)ns * NBATCH * 4 * DMODEL;
}
__host__ __device__ constexpr size_t ws_need(int ns) {
  return MPART_OFF + (mpart_uints(ns) + vpart_elems(ns)) * 4;  // ~36.6 MB @ NS=16
}

typedef short bfrag  __attribute__((ext_vector_type(8)));   // 8 bf16 (4 VGPRs)
typedef float facc   __attribute__((ext_vector_type(4)));   // 4 fp32 acc
typedef float f32x4v __attribute__((ext_vector_type(4)));
typedef unsigned u32x4v __attribute__((ext_vector_type(4)));

__device__ __forceinline__ unsigned pk2(float a, float b) {
  __hip_bfloat162 t = __float22bfloat162_rn(make_float2(a, b));  // v_cvt_pk_bf16_f32
  union { __hip_bfloat162 h; unsigned u; } cc; cc.h = t; return cc.u;
}

__device__ __forceinline__ float selc(const float4& v, int c) {
  return c == 0 ? v.x : c == 1 ? v.y : c == 2 ? v.z : v.w;
}
__device__ __forceinline__ unsigned selu(const uint4& v, int c) {
  return c == 0 ? v.x : c == 1 ? v.y : c == 2 ? v.z : v.w;
}

// non-temporal float4 / uint4 loads (global_load_dwordx4 ... nt)
__device__ __forceinline__ float4 ldnt4(const float* p) {
  f32x4v v = __builtin_nontemporal_load((const f32x4v*)p);
  float4 r; r.x = v.x; r.y = v.y; r.z = v.z; r.w = v.w; return r;
}
__device__ __forceinline__ uint4 ldnt4u(const unsigned* p) {
  u32x4v v = __builtin_nontemporal_load((const u32x4v*)p);
  uint4 r; r.x = v.x; r.y = v.y; r.z = v.z; r.w = v.w; return r;
}

// bf16(low/high half of uint) -> f32
__device__ __forceinline__ float bflo(unsigned u) {
  union { unsigned u; float f; } c; c.u = u << 16; return c.f;
}
__device__ __forceinline__ float bfhi(unsigned u) {
  union { unsigned u; float f; } c; c.u = u & 0xffff0000u; return c.f;
}

// ---------------------------------------------------------------------------
// Kernel 1: partial M[b][d'][d] = sum_{t in chunk} w_t h[b][t][d'] e[b][t][d]
// R8 verbatim (measured 46.9 us; at its mixed L2/HBM per-CU delivery floor).
// ---------------------------------------------------------------------------
template <int NS>
__global__ __launch_bounds__(512, 2) void gemm_m_kernel(
    const float* __restrict__ h, const float* __restrict__ e,
    unsigned* __restrict__ Mout, float* __restrict__ vout)
{
  __shared__ short Al[TM * PK];   // 20 KB
  __shared__ short Bl[TN * PK];   // 20 KB

  constexpr int KCH = S_LEN / NS;

  // bijective XCD swizzle (grid % 8 == 0): XCD x gets logical [x*32, +32)
  // = one bb, contiguous kt-range, all 4 (mt,nt) -> full panel reuse in-XCD.
  const int sidx = blockIdx.x;
  const int blk  = (sidx & 7) * (int)(gridDim.x >> 3) + (sidx >> 3);

  const int nt  = blk & 1;
  const int mt  = (blk >> 1) & 1;
  const int kt  = (blk >> 2) % NS;
  const int bb  = blk / (4 * NS);

  const int tid   = threadIdx.x;
  const bool isB  = (tid >= 256);      // wave-uniform (waves 4..7)
  const int hid   = tid & 255;
  const int col4  = (hid >> 2) * 4;    // 0..252 within the 256-wide tile
  const int trow  = hid & 3;           // t-rows trow*8 .. trow*8+7

  const int wv   = tid >> 6;           // 8 waves -> 2x4 of 128x64 subtiles
  const int wm   = wv >> 2;            // 0..1 (row half)
  const int wn   = wv & 3;             // 0..3 (col quarter)
  const int lane = tid & 63;
  const int lm   = lane & 15, q = lane >> 4;

  const float* src = (isB ? e : h) + (size_t)bb * S_LEN * DMODEL
                   + (isB ? nt * TN : mt * TM) + col4;
  short* ldst = (isB ? Bl : Al) + col4 * PK + trow * 8;

  facc acc[8][4];
#pragma unroll
  for (int i = 0; i < 8; ++i)
#pragma unroll
    for (int j = 0; j < 4; ++j) acc[i][j] = (facc){0.f, 0.f, 0.f, 0.f};

  const float lnA = -(float)M_PI / (float)S_LEN;   // log(alpha), negative
  const int tstart = kt * KCH, tend = tstart + KCH;

  float wbase = __expf(lnA * (float)(S_LEN - 1 - tstart - trow * 8));
  const float stepw = __expf(-lnA * (float)BK);    // alpha^(-32)
  float cr[8];
#pragma unroll
  for (int r = 0; r < 8; ++r)
    cr[r] = __expf(-lnA * (float)r);               // alpha^(-r)

  float4 vacc4 = {0.f, 0.f, 0.f, 0.f};

  // ---- preload iter 0 (nt) ----
  float4 cur[8];
  {
    const float* p = src + (size_t)(tstart + trow * 8) * DMODEL;
#pragma unroll
    for (int r = 0; r < 8; ++r) cur[r] = ldnt4(p + (size_t)r * DMODEL);
  }

  for (int t0 = tstart; t0 < tend; t0 += BK) {
    // ---- scale (B only) + v accumulate ----
    if (isB) {
#pragma unroll
      for (int r = 0; r < 8; ++r) {
        const float w = wbase * cr[r];
        cur[r].x *= w; cur[r].y *= w; cur[r].z *= w; cur[r].w *= w;
      }
      if (mt == 0) {
#pragma unroll
        for (int r = 0; r < 8; ++r) {
          vacc4.x += cur[r].x; vacc4.y += cur[r].y;
          vacc4.z += cur[r].z; vacc4.w += cur[r].w;
        }
      }
    }
    wbase *= stepw;

    // ---- packed bf16 convert + register transpose (frees cur) ----
    uint4 pk[4];
#pragma unroll
    for (int c = 0; c < 4; ++c) {
      pk[c].x = pk2(selc(cur[0], c), selc(cur[1], c));
      pk[c].y = pk2(selc(cur[2], c), selc(cur[3], c));
      pk[c].z = pk2(selc(cur[4], c), selc(cur[5], c));
      pk[c].w = pk2(selc(cur[6], c), selc(cur[7], c));
    }

    // ---- issue next tile's loads (prefetch distance ~= one iteration) ----
    if (t0 + BK < tend) {
      const float* p = src + (size_t)(t0 + BK + trow * 8) * DMODEL;
#pragma unroll
      for (int r = 0; r < 8; ++r) cur[r] = ldnt4(p + (size_t)r * DMODEL);
    }

    __syncthreads();   // previous iteration's frag reads done
#pragma unroll
    for (int c = 0; c < 4; ++c)
      *(uint4*)(ldst + c * PK) = pk[c];
    __syncthreads();

    bfrag af[8], bf[4];
#pragma unroll
    for (int i = 0; i < 8; ++i)
      af[i] = *(const bfrag*)&Al[(wm * 128 + i * 16 + lm) * PK + q * 8];
#pragma unroll
    for (int j = 0; j < 4; ++j)
      bf[j] = *(const bfrag*)&Bl[(wn * 64 + j * 16 + lm) * PK + q * 8];
#pragma unroll
    for (int i = 0; i < 8; ++i)
#pragma unroll
      for (int j = 0; j < 4; ++j)
        acc[i][j] = __builtin_amdgcn_mfma_f32_16x16x32_bf16(af[i], bf[j], acc[i][j], 0, 0, 0);
  }

  // ---- bf16 row-pair partial store: uint[row>>1][col] = (lo=r_even, hi=r_odd)
  {
    unsigned* Mp = Mout + (size_t)blk * (TM * TN / 2);
#pragma unroll
    for (int i = 0; i < 8; ++i)
#pragma unroll
      for (int j = 0; j < 4; ++j) {
        const int pbase = wm * 64 + i * 8 + q * 2;       // (row>>1) base
        const int col   = wn * 64 + j * 16 + lm;
        Mp[(pbase + 0) * TN + col] = pk2(acc[i][j][0], acc[i][j][1]);
        Mp[(pbase + 1) * TN + col] = pk2(acc[i][j][2], acc[i][j][3]);
      }
    if (isB && mt == 0) {
      *(float4*)&vout[(size_t)((kt * NBATCH + bb) * 4 + trow) * DMODEL
                      + nt * TN + col4] = vacc4;
    }
  }
}

// ---------------------------------------------------------------------------
// Reduce: Mredb(bf16 row-pairs) = sum_kt Mpart(bf16 pairs); vws = sum vpart.
// 512 blocks x 256 thr; each thread: one uint4 (4 cols x 2 rows) x NS, nt
// loads (streaming, no reuse), packs the fp32 sums back to row-pair uints.
// ---------------------------------------------------------------------------
template <int NS>
__global__ __launch_bounds__(256) void reduce_kernel(
    const unsigned* __restrict__ Mpart, const float* __restrict__ vpart,
    unsigned* __restrict__ Mredb, float* __restrict__ vws)
{
  const int gid = blockIdx.x * 256 + threadIdx.x;    // one uint4 each
  const int bb     = gid >> 15;          // 32768 uint4 per batch
  const int rem    = gid & 32767;
  const int tile   = rem >> 13;          // 4 tiles (mt*2+nt)
  const int within = rem & 8191;         // uint4 index inside tile

  const int pr  = within >> 6;           // pair-row 0..127
  const int c4  = (within & 63) * 4;     // col base (uint4-aligned)

  constexpr size_t TILESZ_U = (size_t)TM * TN / 2;   // 32768 uints
  const size_t base = ((size_t)(bb * NS) * 4 + tile) * TILESZ_U
                    + (size_t)pr * TN + c4;

  float4 s0 = {0.f, 0.f, 0.f, 0.f};      // even row
  float4 s1 = {0.f, 0.f, 0.f, 0.f};      // odd row
#pragma unroll
  for (int kt = 0; kt < NS; ++kt) {
    const uint4 v = ldnt4u(&Mpart[base + (size_t)kt * 4 * TILESZ_U]);
    s0.x += bflo(v.x); s1.x += bfhi(v.x);
    s0.y += bflo(v.y); s1.y += bfhi(v.y);
    s0.z += bflo(v.z); s1.z += bfhi(v.z);
    s0.w += bflo(v.w); s1.w += bfhi(v.w);
  }
  const int mt = tile >> 1, ntt = tile & 1;
  const int gpr  = mt * (TM / 2) + pr;   // global pair-row 0..255
  const int gcol = ntt * TN + c4;
  uint4 o;
  o.x = pk2(s0.x, s1.x); o.y = pk2(s0.y, s1.y);
  o.z = pk2(s0.z, s1.z); o.w = pk2(s0.w, s1.w);
  *(uint4*)&Mredb[(size_t)bb * (DMODEL * DMODEL / 2)
                  + (size_t)gpr * DMODEL + gcol] = o;

  if (gid < (NBATCH * DMODEL / 4)) {     // 512 threads: v reduction
    const int vb = gid >> 7;
    const int vc = (gid & 127) * 4;
    float4 vs = {0.f, 0.f, 0.f, 0.f};
#pragma unroll
    for (int kt = 0; kt < NS; ++kt)
#pragma unroll
      for (int tr = 0; tr < 4; ++tr) {
        const float4 v = *(const float4*)&vpart[(size_t)((kt * NBATCH + vb) * 4 + tr) * DMODEL + vc];
        vs.x += v.x; vs.y += v.y; vs.z += v.z; vs.w += v.w;
      }
    *(float4*)&vws[vb * DMODEL + vc] = vs;
  }
}

// ---------------------------------------------------------------------------
// Kernel 3: C[b][s][d] = sum_{d'} W[s][d'] Mredb[b][d'][d] + bias[s]*v[b][d]
// 64x64 tiles, K=512, 16 pipelined iters. M-side now reads bf16 row-pairs:
// 2 uint4 loads/iter/thread, zero conversion, same LDS layout as before
// (uint2 at [col*PKC + mrow4] = rows mrow4..+3 of one column).
// ---------------------------------------------------------------------------
__global__ __launch_bounds__(256) void gemm_c_kernel(
    const float* __restrict__ Wmat, const float* __restrict__ bias,
    const unsigned* __restrict__ Mredb, const float* __restrict__ vws,
    float* __restrict__ out)
{
  __shared__ short Wl[64 * PKC];
  __shared__ short Ml[64 * PKC];

  const int blk = blockIdx.x;          // grid = 4 * 8 * 8 = 256
  const int ntc = blk & 7;
  const int mtc = (blk >> 3) & 7;
  const int bb  = blk >> 6;

  const int tid  = threadIdx.x;
  const bool isM = (tid >= 128);
  const int hid  = tid & 127;
  const int arow = hid & 63;           // W-half
  const int ahalf = (hid >> 6) * 16;
  const int mcol4 = (hid & 15) * 4;    // M-half: 4 cols
  const int mrow4 = (hid >> 4) * 4;    // M-half: 4 rows (= 2 pair-rows)

  const int wv   = tid >> 6;
  const int lane = tid & 63;
  const int lm   = lane & 15, q = lane >> 4;

  const unsigned* Mb = Mredb + (size_t)bb * (DMODEL * DMODEL / 2);

  facc acc[4];
#pragma unroll
  for (int j = 0; j < 4; ++j) acc[j] = (facc){0.f, 0.f, 0.f, 0.f};

  float4 wcur[4];
  uint4  mcur[2];
  if (!isM) {
    const float* p = &Wmat[(size_t)(mtc * 64 + arow) * DMODEL + ahalf];
#pragma unroll
    for (int r = 0; r < 4; ++r) wcur[r] = *(const float4*)(p + r * 4);
  } else {
    const unsigned* p = Mb + (size_t)(mrow4 >> 1) * DMODEL + ntc * 64 + mcol4;
    mcur[0] = *(const uint4*)p;            // rows mrow4, mrow4+1 (lo/hi)
    mcur[1] = *(const uint4*)(p + DMODEL); // rows mrow4+2, mrow4+3
  }

  for (int k0 = 0; k0 < DMODEL; k0 += CBK) {
    uint4 pw0, pw1;
    uint2 pm[4];
    if (!isM) {
      pw0.x = pk2(wcur[0].x, wcur[0].y); pw0.y = pk2(wcur[0].z, wcur[0].w);
      pw0.z = pk2(wcur[1].x, wcur[1].y); pw0.w = pk2(wcur[1].z, wcur[1].w);
      pw1.x = pk2(wcur[2].x, wcur[2].y); pw1.y = pk2(wcur[2].z, wcur[2].w);
      pw1.z = pk2(wcur[3].x, wcur[3].y); pw1.w = pk2(wcur[3].z, wcur[3].w);
    } else {
#pragma unroll
      for (int c = 0; c < 4; ++c) {
        pm[c].x = selu(mcur[0], c);        // rows mrow4, +1
        pm[c].y = selu(mcur[1], c);        // rows mrow4+2, +3
      }
    }

    if (k0 + CBK < DMODEL) {
      if (!isM) {
        const float* p = &Wmat[(size_t)(mtc * 64 + arow) * DMODEL + k0 + CBK + ahalf];
#pragma unroll
        for (int r = 0; r < 4; ++r) wcur[r] = *(const float4*)(p + r * 4);
      } else {
        const unsigned* p = Mb + (size_t)((k0 + CBK + mrow4) >> 1) * DMODEL
                          + ntc * 64 + mcol4;
        mcur[0] = *(const uint4*)p;
        mcur[1] = *(const uint4*)(p + DMODEL);
      }
    }

    __syncthreads();
    if (!isM) {
      *(uint4*)&Wl[arow * PKC + ahalf]     = pw0;
      *(uint4*)&Wl[arow * PKC + ahalf + 8] = pw1;
    } else {
#pragma unroll
      for (int c = 0; c < 4; ++c)
        *(uint2*)&Ml[(mcol4 + c) * PKC + mrow4] = pm[c];
    }
    __syncthreads();

    bfrag af, bf[4];
    af = *(const bfrag*)&Wl[(wv * 16 + lm) * PKC + q * 8];
#pragma unroll
    for (int j = 0; j < 4; ++j)
      bf[j] = *(const bfrag*)&Ml[(j * 16 + lm) * PKC + q * 8];
#pragma unroll
    for (int j = 0; j < 4; ++j)
      acc[j] = __builtin_amdgcn_mfma_f32_16x16x32_bf16(af, bf[j], acc[j], 0, 0, 0);
  }

#pragma unroll
  for (int j = 0; j < 4; ++j)
#pragma unroll
    for (int r = 0; r < 4; ++r) {
      const int row = mtc * 64 + wv * 16 + q * 4 + r;   // s
      const int col = ntc * 64 + j * 16 + lm;           // d
      out[((size_t)bb * DMODEL + row) * DMODEL + col] =
          acc[j][r] + bias[row] * vws[bb * DMODEL + col];
    }
}

// ---------------------------------------------------------------------------
extern "C" void kernel_launch(void* const* d_in, const int* in_sizes, int n_in,
                              void* d_out, int out_size, void* d_ws, size_t ws_size,
                              hipStream_t stream) {
  const float* h    = (const float*)d_in[0];   // (4, 8192, 512) fp32
  const float* e    = (const float*)d_in[1];   // (4, 8192, 512) fp32
  const float* Wmat = (const float*)d_in[2];   // (512, 512) fp32
  const float* bias = (const float*)d_in[3];   // (512,) fp32
  float* out = (float*)d_out;                  // (4, 512, 512) fp32

  unsigned* Mredb = (unsigned*)((char*)d_ws + MRED_OFF);
  float*    vws   = (float*)((char*)d_ws + VWS_OFF);
  unsigned* Mpart = (unsigned*)((char*)d_ws + MPART_OFF);

  constexpr int NS = 16;                       // grid 256 (R0 config)
  float* vpart = (float*)(Mpart + mpart_uints(NS));
  gemm_m_kernel<NS><<<NBATCH * NS * 4, 512, 0, stream>>>(h, e, Mpart, vpart);
  reduce_kernel<NS><<<512, 256, 0, stream>>>(Mpart, vpart, Mredb, vws);
  gemm_c_kernel<<<NBATCH * 64, 256, 0, stream>>>(Wmat, bias, Mredb, vws, out);
}